// Round 3
// baseline (831.494 us; speedup 1.0000x reference)
//
#include <hip/hip_runtime.h>

#define IC 4096
#define NWAVES 8
#define IPW 4        // i-values register-cached per wave
#define NB 8         // batch elements accumulated in regs between reductions
#define BHALF 128    // batch elements per block

// One routing pass: for each (b,i) recompute u[a,d] = sum_c x[b,i,c]*W[a,i,d,c],
// weight by c[a] (uniform 1/16 if USEV==0, else softmax over a of IC*(u . vprev)),
// and accumulate s_rep[rep][b][a][d] += c[a]*u[a,d].
// launch_bounds(512,1): full 256-VGPR budget so the 128-float W cache can live
// in registers (with (512,2) the allocator capped at 128 VGPR and spilled).
template<int USEV>
__global__ __launch_bounds__(512, 1)
void caps_pass(const float* __restrict__ x, const float* __restrict__ W,
               const float* __restrict__ vprev, float* __restrict__ s_rep,
               int n_rep)
{
    __shared__ float lds[NWAVES][NB][256];
    const int tid  = threadIdx.x;
    const int wu   = __builtin_amdgcn_readfirstlane(tid >> 6);  // wave id 0..7
    const int lane = tid & 63;
    const int a    = lane >> 2;   // capsule 0..15
    const int dq   = lane & 3;    // d-quad: lane owns d = dq*4 .. dq*4+3
    const int ichunk = (int)blockIdx.x >> 1;
    const int bhalf  = (int)blockIdx.x & 1;
    const int i0 = ichunk * (NWAVES * IPW) + wu * IPW;
    const int rep = (int)blockIdx.x & (n_rep - 1);
    float* srep = s_rep + (size_t)rep * 65536;

    // Register-cache W[a, i0..i0+3, dq*4..dq*4+3, 0..7]: 32 contiguous floats per i.
    float w[IPW][32];
#pragma unroll
    for (int ii = 0; ii < IPW; ++ii) {
        const float* wp = W + ((size_t)a * IC + (size_t)(i0 + ii)) * 128 + dq * 32;
#pragma unroll
        for (int q = 0; q < 8; ++q) {
            const float4 f = *(const float4*)(wp + q * 4);
            w[ii][q * 4 + 0] = f.x; w[ii][q * 4 + 1] = f.y;
            w[ii][q * 4 + 2] = f.z; w[ii][q * 4 + 3] = f.w;
        }
    }
    // Pin the W cache: opaque asm blocks rematerialization of the loads.
#pragma unroll
    for (int ii = 0; ii < IPW; ++ii)
#pragma unroll
        for (int k = 0; k < 32; ++k)
            asm volatile("" : "+v"(w[ii][k]));

    const int b0 = bhalf * BHALF;
    for (int ph = 0; ph < BHALF / NB; ++ph) {
        float sl[NB][4];
#pragma unroll
        for (int nb = 0; nb < NB; ++nb) {
            sl[nb][0] = 0.f; sl[nb][1] = 0.f; sl[nb][2] = 0.f; sl[nb][3] = 0.f;
            const int b = b0 + ph * NB + nb;
            float4 va;
            if (USEV)  // ii-invariant: hoisted out of the ii loop
                va = *(const float4*)(vprev + (((size_t)b * 16 + a) * 16 + dq * 4));
#pragma unroll
            for (int ii = 0; ii < IPW; ++ii) {
                const float* xp = x + ((size_t)b * IC + (size_t)(i0 + ii)) * 8;
                const float4 xa = *(const float4*)(xp);
                const float4 xb = *(const float4*)(xp + 4);
                float u0, u1, u2, u3;
                u0 = xa.x * w[ii][0];
                u1 = xa.x * w[ii][8];
                u2 = xa.x * w[ii][16];
                u3 = xa.x * w[ii][24];
                u0 = fmaf(xa.y, w[ii][1],  u0); u1 = fmaf(xa.y, w[ii][9],  u1);
                u2 = fmaf(xa.y, w[ii][17], u2); u3 = fmaf(xa.y, w[ii][25], u3);
                u0 = fmaf(xa.z, w[ii][2],  u0); u1 = fmaf(xa.z, w[ii][10], u1);
                u2 = fmaf(xa.z, w[ii][18], u2); u3 = fmaf(xa.z, w[ii][26], u3);
                u0 = fmaf(xa.w, w[ii][3],  u0); u1 = fmaf(xa.w, w[ii][11], u1);
                u2 = fmaf(xa.w, w[ii][19], u2); u3 = fmaf(xa.w, w[ii][27], u3);
                u0 = fmaf(xb.x, w[ii][4],  u0); u1 = fmaf(xb.x, w[ii][12], u1);
                u2 = fmaf(xb.x, w[ii][20], u2); u3 = fmaf(xb.x, w[ii][28], u3);
                u0 = fmaf(xb.y, w[ii][5],  u0); u1 = fmaf(xb.y, w[ii][13], u1);
                u2 = fmaf(xb.y, w[ii][21], u2); u3 = fmaf(xb.y, w[ii][29], u3);
                u0 = fmaf(xb.z, w[ii][6],  u0); u1 = fmaf(xb.z, w[ii][14], u1);
                u2 = fmaf(xb.z, w[ii][22], u2); u3 = fmaf(xb.z, w[ii][30], u3);
                u0 = fmaf(xb.w, w[ii][7],  u0); u1 = fmaf(xb.w, w[ii][15], u1);
                u2 = fmaf(xb.w, w[ii][23], u2); u3 = fmaf(xb.w, w[ii][31], u3);
                float cw;
                if (USEV == 0) {
                    cw = 1.0f / 16.0f;
                } else {
                    // agree = u . vprev  (vprev = v1, or v1+v2 for the last pass)
                    float ag = u0 * va.x + u1 * va.y + u2 * va.z + u3 * va.w;
                    ag += __shfl_xor(ag, 1);   // combine d-quads within the a-group
                    ag += __shfl_xor(ag, 2);
                    const float blog = 4096.0f * ag;
                    // softmax over the 16 capsules (4-lane groups); strides 4..32
                    // don't touch lane bits 0-1 so replicated values sum once per a.
                    float m = blog;
                    m = fmaxf(m, __shfl_xor(m, 4));
                    m = fmaxf(m, __shfl_xor(m, 8));
                    m = fmaxf(m, __shfl_xor(m, 16));
                    m = fmaxf(m, __shfl_xor(m, 32));
                    const float e = __expf(blog - m);
                    float sum = e;
                    sum += __shfl_xor(sum, 4);
                    sum += __shfl_xor(sum, 8);
                    sum += __shfl_xor(sum, 16);
                    sum += __shfl_xor(sum, 32);
                    cw = __fdividef(e, sum);
                }
                sl[nb][0] = fmaf(cw, u0, sl[nb][0]);
                sl[nb][1] = fmaf(cw, u1, sl[nb][1]);
                sl[nb][2] = fmaf(cw, u2, sl[nb][2]);
                sl[nb][3] = fmaf(cw, u3, sl[nb][3]);
            }
        }
        // ---- reduction phase: 8 b's at once ----
#pragma unroll
        for (int nb = 0; nb < NB; ++nb)
            *(float4*)&lds[wu][nb][lane * 4] =
                make_float4(sl[nb][0], sl[nb][1], sl[nb][2], sl[nb][3]);
        __syncthreads();
        {
            const int bsel = tid >> 6;          // 0..7
            const int ad4  = (tid & 63) * 4;    // 0..252
            float4 acc = make_float4(0.f, 0.f, 0.f, 0.f);
#pragma unroll
            for (int wv = 0; wv < NWAVES; ++wv) {
                const float4 f = *(const float4*)&lds[wv][bsel][ad4];
                acc.x += f.x; acc.y += f.y; acc.z += f.z; acc.w += f.w;
            }
            float* dst = srep + (size_t)(b0 + ph * NB + bsel) * 256 + ad4;
            unsafeAtomicAdd(dst + 0, acc.x);
            unsafeAtomicAdd(dst + 1, acc.y);
            unsafeAtomicAdd(dst + 2, acc.z);
            unsafeAtomicAdd(dst + 3, acc.w);
        }
        __syncthreads();
    }
}

// v = squash(sum_r s_rep[r]) [+ vprev]; optionally re-zero srep for next pass.
// One thread per (b, a): 4096 threads.
template<int ADDP, int ZERO>
__global__ void caps_squash(float* __restrict__ srep, int n_rep,
                            float* __restrict__ vout, const float* __restrict__ vprev)
{
    const int t = (int)blockIdx.x * 256 + (int)threadIdx.x;  // 0..4095
    float4 f0 = make_float4(0.f, 0.f, 0.f, 0.f), f1 = f0, f2 = f0, f3 = f0;
    for (int r = 0; r < n_rep; ++r) {
        float* sp = srep + (size_t)r * 65536 + (size_t)t * 16;
        const float4 a0 = *(const float4*)(sp + 0);
        const float4 a1 = *(const float4*)(sp + 4);
        const float4 a2 = *(const float4*)(sp + 8);
        const float4 a3 = *(const float4*)(sp + 12);
        f0.x += a0.x; f0.y += a0.y; f0.z += a0.z; f0.w += a0.w;
        f1.x += a1.x; f1.y += a1.y; f1.z += a1.z; f1.w += a1.w;
        f2.x += a2.x; f2.y += a2.y; f2.z += a2.z; f2.w += a2.w;
        f3.x += a3.x; f3.y += a3.y; f3.z += a3.z; f3.w += a3.w;
        if (ZERO) {
            const float4 z = make_float4(0.f, 0.f, 0.f, 0.f);
            *(float4*)(sp + 0) = z; *(float4*)(sp + 4) = z;
            *(float4*)(sp + 8) = z; *(float4*)(sp + 12) = z;
        }
    }
    float sq = f0.x * f0.x + f0.y * f0.y + f0.z * f0.z + f0.w * f0.w
             + f1.x * f1.x + f1.y * f1.y + f1.z * f1.z + f1.w * f1.w
             + f2.x * f2.x + f2.y * f2.y + f2.z * f2.z + f2.w * f2.w
             + f3.x * f3.x + f3.y * f3.y + f3.z * f3.z + f3.w * f3.w;
    const float scale = sq / ((1.0f + sq) * sqrtf(sq + 1e-7f));
    float4 o0, o1, o2, o3;
    o0.x = f0.x * scale; o0.y = f0.y * scale; o0.z = f0.z * scale; o0.w = f0.w * scale;
    o1.x = f1.x * scale; o1.y = f1.y * scale; o1.z = f1.z * scale; o1.w = f1.w * scale;
    o2.x = f2.x * scale; o2.y = f2.y * scale; o2.z = f2.z * scale; o2.w = f2.w * scale;
    o3.x = f3.x * scale; o3.y = f3.y * scale; o3.z = f3.z * scale; o3.w = f3.w * scale;
    if (ADDP) {
        const float* pp = vprev + (size_t)t * 16;
        const float4 p0 = *(const float4*)(pp + 0);
        const float4 p1 = *(const float4*)(pp + 4);
        const float4 p2 = *(const float4*)(pp + 8);
        const float4 p3 = *(const float4*)(pp + 12);
        o0.x += p0.x; o0.y += p0.y; o0.z += p0.z; o0.w += p0.w;
        o1.x += p1.x; o1.y += p1.y; o1.z += p1.z; o1.w += p1.w;
        o2.x += p2.x; o2.y += p2.y; o2.z += p2.z; o2.w += p2.w;
        o3.x += p3.x; o3.y += p3.y; o3.z += p3.z; o3.w += p3.w;
    }
    float* vp = vout + (size_t)t * 16;
    *(float4*)(vp + 0)  = o0;
    *(float4*)(vp + 4)  = o1;
    *(float4*)(vp + 8)  = o2;
    *(float4*)(vp + 12) = o3;
}

__global__ void caps_zero(float* __restrict__ p)
{
    *(float4*)(p + ((size_t)blockIdx.x * 256 + threadIdx.x) * 4) =
        make_float4(0.f, 0.f, 0.f, 0.f);
}

extern "C" void kernel_launch(void* const* d_in, const int* in_sizes, int n_in,
                              void* d_out, int out_size, void* d_ws, size_t ws_size,
                              hipStream_t stream)
{
    const float* x = (const float*)d_in[0];   // [256, 4096, 8]
    const float* W = (const float*)d_in[1];   // [16, 4096, 16, 8]
    float* out = (float*)d_out;               // [256, 16, 16]

    // pick replica count by available workspace: (R + 2) * 256 KB needed
    int R = 1;
    if (ws_size >= (size_t)(8 + 2) * 65536 * 4) R = 8;
    else if (ws_size >= (size_t)(2 + 2) * 65536 * 4) R = 2;

    float* srep = (float*)d_ws;               // R * 65536 floats
    float* v1   = srep + (size_t)R * 65536;
    float* vs   = v1 + 65536;

    caps_zero<<<R * 64, 256, 0, stream>>>(srep);
    // iter 1: uniform coupling c = 1/16
    caps_pass<0><<<256, 512, 0, stream>>>(x, W, nullptr, srep, R);
    caps_squash<0, 1><<<16, 256, 0, stream>>>(srep, R, v1, nullptr);   // v1 = squash(s); s=0
    // iter 2: logits = IC * (u . v1)
    caps_pass<1><<<256, 512, 0, stream>>>(x, W, v1, srep, R);
    caps_squash<1, 1><<<16, 256, 0, stream>>>(srep, R, vs, v1);        // vs = squash(s)+v1; s=0
    // iter 3: logits = IC * (u.v1 + u.v2) = IC * (u . vs)
    caps_pass<1><<<256, 512, 0, stream>>>(x, W, vs, srep, R);
    caps_squash<0, 0><<<16, 256, 0, stream>>>(srep, R, out, nullptr);  // out = squash(s)
}

// Round 4
// 611.047 us; speedup vs baseline: 1.3608x; 1.3608x over previous
//
#include <hip/hip_runtime.h>

#define IC 4096
#define NWAVES 8
#define IPW 4        // i-values register-cached per wave
#define NB 4         // batch elements accumulated in regs between reductions
#define BHALF 128    // batch elements per block

// One routing pass: for each (b,i) recompute u[a,d] = sum_c x[b,i,c]*W[a,i,d,c],
// weight by c[a] (uniform 1/16 if USEV==0, else softmax over a of IC*(u . vprev)),
// and accumulate s_rep[rep][b][a][d] += c[a]*u[a,d].
//
// amdgpu_waves_per_eu(2,2): hard occupancy range. The allocator's default
// occupancy target (~5 waves/EU -> ~96-VGPR budget) made it SPILL the 128-float
// W register cache to scratch in rounds 2-3 (WRITE_SIZE 33->131 MB).
// __launch_bounds__'s 2nd arg is only a lower bound and cannot raise the
// budget; this attribute pins the target to 2 waves/EU => 256-VGPR budget.
template<int USEV>
__global__ __launch_bounds__(512)
__attribute__((amdgpu_waves_per_eu(2, 2)))
void caps_pass(const float* __restrict__ x, const float* __restrict__ W,
               const float* __restrict__ vprev, float* __restrict__ s_rep,
               int n_rep)
{
    __shared__ float lds[NWAVES][NB][256];
    const int tid  = threadIdx.x;
    const int wu   = __builtin_amdgcn_readfirstlane(tid >> 6);  // wave id 0..7
    const int lane = tid & 63;
    const int a    = lane >> 2;   // capsule 0..15
    const int dq   = lane & 3;    // d-quad: lane owns d = dq*4 .. dq*4+3
    const int ichunk = (int)blockIdx.x >> 1;
    const int bhalf  = (int)blockIdx.x & 1;
    const int i0 = ichunk * (NWAVES * IPW) + wu * IPW;
    const int rep = (int)blockIdx.x & (n_rep - 1);
    float* srep = s_rep + (size_t)rep * 65536;

    // Register-cache W[a, i0..i0+3, dq*4..dq*4+3, 0..7]: 32 contiguous floats per i.
    float w[IPW][32];
#pragma unroll
    for (int ii = 0; ii < IPW; ++ii) {
        const float* wp = W + ((size_t)a * IC + (size_t)(i0 + ii)) * 128 + dq * 32;
#pragma unroll
        for (int q = 0; q < 8; ++q) {
            const float4 f = *(const float4*)(wp + q * 4);
            w[ii][q * 4 + 0] = f.x; w[ii][q * 4 + 1] = f.y;
            w[ii][q * 4 + 2] = f.z; w[ii][q * 4 + 3] = f.w;
        }
    }
    // Pin the W cache: opaque asm blocks rematerialization of the loads.
#pragma unroll
    for (int ii = 0; ii < IPW; ++ii)
#pragma unroll
        for (int k = 0; k < 32; ++k)
            asm volatile("" : "+v"(w[ii][k]));

    const int b0 = bhalf * BHALF;
    for (int ph = 0; ph < BHALF / NB; ++ph) {
        float sl[NB][4];
#pragma unroll
        for (int nb = 0; nb < NB; ++nb) {
            sl[nb][0] = 0.f; sl[nb][1] = 0.f; sl[nb][2] = 0.f; sl[nb][3] = 0.f;
            const int b = b0 + ph * NB + nb;
            float4 va;
            if (USEV)  // ii-invariant: hoisted out of the ii loop
                va = *(const float4*)(vprev + (((size_t)b * 16 + a) * 16 + dq * 4));
#pragma unroll
            for (int ii = 0; ii < IPW; ++ii) {
                const float* xp = x + ((size_t)b * IC + (size_t)(i0 + ii)) * 8;
                const float4 xa = *(const float4*)(xp);
                const float4 xb = *(const float4*)(xp + 4);
                float u0, u1, u2, u3;
                u0 = xa.x * w[ii][0];
                u1 = xa.x * w[ii][8];
                u2 = xa.x * w[ii][16];
                u3 = xa.x * w[ii][24];
                u0 = fmaf(xa.y, w[ii][1],  u0); u1 = fmaf(xa.y, w[ii][9],  u1);
                u2 = fmaf(xa.y, w[ii][17], u2); u3 = fmaf(xa.y, w[ii][25], u3);
                u0 = fmaf(xa.z, w[ii][2],  u0); u1 = fmaf(xa.z, w[ii][10], u1);
                u2 = fmaf(xa.z, w[ii][18], u2); u3 = fmaf(xa.z, w[ii][26], u3);
                u0 = fmaf(xa.w, w[ii][3],  u0); u1 = fmaf(xa.w, w[ii][11], u1);
                u2 = fmaf(xa.w, w[ii][19], u2); u3 = fmaf(xa.w, w[ii][27], u3);
                u0 = fmaf(xb.x, w[ii][4],  u0); u1 = fmaf(xb.x, w[ii][12], u1);
                u2 = fmaf(xb.x, w[ii][20], u2); u3 = fmaf(xb.x, w[ii][28], u3);
                u0 = fmaf(xb.y, w[ii][5],  u0); u1 = fmaf(xb.y, w[ii][13], u1);
                u2 = fmaf(xb.y, w[ii][21], u2); u3 = fmaf(xb.y, w[ii][29], u3);
                u0 = fmaf(xb.z, w[ii][6],  u0); u1 = fmaf(xb.z, w[ii][14], u1);
                u2 = fmaf(xb.z, w[ii][22], u2); u3 = fmaf(xb.z, w[ii][30], u3);
                u0 = fmaf(xb.w, w[ii][7],  u0); u1 = fmaf(xb.w, w[ii][15], u1);
                u2 = fmaf(xb.w, w[ii][23], u2); u3 = fmaf(xb.w, w[ii][31], u3);
                float cw;
                if (USEV == 0) {
                    cw = 1.0f / 16.0f;
                } else {
                    // agree = u . vprev  (vprev = v1, or v1+v2 for the last pass)
                    float ag = u0 * va.x + u1 * va.y + u2 * va.z + u3 * va.w;
                    ag += __shfl_xor(ag, 1);   // combine d-quads within the a-group
                    ag += __shfl_xor(ag, 2);
                    const float blog = 4096.0f * ag;
                    // softmax over the 16 capsules (4-lane groups); strides 4..32
                    // don't touch lane bits 0-1 so replicated values sum once per a.
                    float m = blog;
                    m = fmaxf(m, __shfl_xor(m, 4));
                    m = fmaxf(m, __shfl_xor(m, 8));
                    m = fmaxf(m, __shfl_xor(m, 16));
                    m = fmaxf(m, __shfl_xor(m, 32));
                    const float e = __expf(blog - m);
                    float sum = e;
                    sum += __shfl_xor(sum, 4);
                    sum += __shfl_xor(sum, 8);
                    sum += __shfl_xor(sum, 16);
                    sum += __shfl_xor(sum, 32);
                    cw = __fdividef(e, sum);
                }
                sl[nb][0] = fmaf(cw, u0, sl[nb][0]);
                sl[nb][1] = fmaf(cw, u1, sl[nb][1]);
                sl[nb][2] = fmaf(cw, u2, sl[nb][2]);
                sl[nb][3] = fmaf(cw, u3, sl[nb][3]);
            }
        }
        // ---- reduction phase: NB b's at once ----
#pragma unroll
        for (int nb = 0; nb < NB; ++nb)
            *(float4*)&lds[wu][nb][lane * 4] =
                make_float4(sl[nb][0], sl[nb][1], sl[nb][2], sl[nb][3]);
        __syncthreads();
        if (tid < NB * 64) {
            const int bsel = tid >> 6;          // 0..NB-1
            const int ad4  = (tid & 63) * 4;    // 0..252
            float4 acc = make_float4(0.f, 0.f, 0.f, 0.f);
#pragma unroll
            for (int wv = 0; wv < NWAVES; ++wv) {
                const float4 f = *(const float4*)&lds[wv][bsel][ad4];
                acc.x += f.x; acc.y += f.y; acc.z += f.z; acc.w += f.w;
            }
            float* dst = srep + (size_t)(b0 + ph * NB + bsel) * 256 + ad4;
            unsafeAtomicAdd(dst + 0, acc.x);
            unsafeAtomicAdd(dst + 1, acc.y);
            unsafeAtomicAdd(dst + 2, acc.z);
            unsafeAtomicAdd(dst + 3, acc.w);
        }
        __syncthreads();
    }
}

// v = squash(sum_r s_rep[r]) [+ vprev]; optionally re-zero srep for next pass.
// One thread per (b, a): 4096 threads.
template<int ADDP, int ZERO>
__global__ void caps_squash(float* __restrict__ srep, int n_rep,
                            float* __restrict__ vout, const float* __restrict__ vprev)
{
    const int t = (int)blockIdx.x * 256 + (int)threadIdx.x;  // 0..4095
    float4 f0 = make_float4(0.f, 0.f, 0.f, 0.f), f1 = f0, f2 = f0, f3 = f0;
    for (int r = 0; r < n_rep; ++r) {
        float* sp = srep + (size_t)r * 65536 + (size_t)t * 16;
        const float4 a0 = *(const float4*)(sp + 0);
        const float4 a1 = *(const float4*)(sp + 4);
        const float4 a2 = *(const float4*)(sp + 8);
        const float4 a3 = *(const float4*)(sp + 12);
        f0.x += a0.x; f0.y += a0.y; f0.z += a0.z; f0.w += a0.w;
        f1.x += a1.x; f1.y += a1.y; f1.z += a1.z; f1.w += a1.w;
        f2.x += a2.x; f2.y += a2.y; f2.z += a2.z; f2.w += a2.w;
        f3.x += a3.x; f3.y += a3.y; f3.z += a3.z; f3.w += a3.w;
        if (ZERO) {
            const float4 z = make_float4(0.f, 0.f, 0.f, 0.f);
            *(float4*)(sp + 0) = z; *(float4*)(sp + 4) = z;
            *(float4*)(sp + 8) = z; *(float4*)(sp + 12) = z;
        }
    }
    float sq = f0.x * f0.x + f0.y * f0.y + f0.z * f0.z + f0.w * f0.w
             + f1.x * f1.x + f1.y * f1.y + f1.z * f1.z + f1.w * f1.w
             + f2.x * f2.x + f2.y * f2.y + f2.z * f2.z + f2.w * f2.w
             + f3.x * f3.x + f3.y * f3.y + f3.z * f3.z + f3.w * f3.w;
    const float scale = sq / ((1.0f + sq) * sqrtf(sq + 1e-7f));
    float4 o0, o1, o2, o3;
    o0.x = f0.x * scale; o0.y = f0.y * scale; o0.z = f0.z * scale; o0.w = f0.w * scale;
    o1.x = f1.x * scale; o1.y = f1.y * scale; o1.z = f1.z * scale; o1.w = f1.w * scale;
    o2.x = f2.x * scale; o2.y = f2.y * scale; o2.z = f2.z * scale; o2.w = f2.w * scale;
    o3.x = f3.x * scale; o3.y = f3.y * scale; o3.z = f3.z * scale; o3.w = f3.w * scale;
    if (ADDP) {
        const float* pp = vprev + (size_t)t * 16;
        const float4 p0 = *(const float4*)(pp + 0);
        const float4 p1 = *(const float4*)(pp + 4);
        const float4 p2 = *(const float4*)(pp + 8);
        const float4 p3 = *(const float4*)(pp + 12);
        o0.x += p0.x; o0.y += p0.y; o0.z += p0.z; o0.w += p0.w;
        o1.x += p1.x; o1.y += p1.y; o1.z += p1.z; o1.w += p1.w;
        o2.x += p2.x; o2.y += p2.y; o2.z += p2.z; o2.w += p2.w;
        o3.x += p3.x; o3.y += p3.y; o3.z += p3.z; o3.w += p3.w;
    }
    float* vp = vout + (size_t)t * 16;
    *(float4*)(vp + 0)  = o0;
    *(float4*)(vp + 4)  = o1;
    *(float4*)(vp + 8)  = o2;
    *(float4*)(vp + 12) = o3;
}

__global__ void caps_zero(float* __restrict__ p)
{
    *(float4*)(p + ((size_t)blockIdx.x * 256 + threadIdx.x) * 4) =
        make_float4(0.f, 0.f, 0.f, 0.f);
}

extern "C" void kernel_launch(void* const* d_in, const int* in_sizes, int n_in,
                              void* d_out, int out_size, void* d_ws, size_t ws_size,
                              hipStream_t stream)
{
    const float* x = (const float*)d_in[0];   // [256, 4096, 8]
    const float* W = (const float*)d_in[1];   // [16, 4096, 16, 8]
    float* out = (float*)d_out;               // [256, 16, 16]

    // pick replica count by available workspace: (R + 2) * 256 KB needed
    int R = 1;
    if (ws_size >= (size_t)(8 + 2) * 65536 * 4) R = 8;
    else if (ws_size >= (size_t)(2 + 2) * 65536 * 4) R = 2;

    float* srep = (float*)d_ws;               // R * 65536 floats
    float* v1   = srep + (size_t)R * 65536;
    float* vs   = v1 + 65536;

    caps_zero<<<R * 64, 256, 0, stream>>>(srep);
    // iter 1: uniform coupling c = 1/16
    caps_pass<0><<<256, 512, 0, stream>>>(x, W, nullptr, srep, R);
    caps_squash<0, 1><<<16, 256, 0, stream>>>(srep, R, v1, nullptr);   // v1 = squash(s); s=0
    // iter 2: logits = IC * (u . v1)
    caps_pass<1><<<256, 512, 0, stream>>>(x, W, v1, srep, R);
    caps_squash<1, 1><<<16, 256, 0, stream>>>(srep, R, vs, v1);        // vs = squash(s)+v1; s=0
    // iter 3: logits = IC * (u.v1 + u.v2) = IC * (u . vs)
    caps_pass<1><<<256, 512, 0, stream>>>(x, W, vs, srep, R);
    caps_squash<0, 0><<<16, 256, 0, stream>>>(srep, R, out, nullptr);  // out = squash(s)
}